// Round 3
// baseline (564.856 us; speedup 1.0000x reference)
//
#include <hip/hip_runtime.h>
#include <cstdint>
#include <cstddef>

typedef __bf16 bf16;
typedef __bf16 bf16x4 __attribute__((ext_vector_type(4)));
typedef __bf16 bf16x8 __attribute__((ext_vector_type(8)));
typedef float  f32x4  __attribute__((ext_vector_type(4)));

// Direct global->LDS DMA, 16B per lane. LDS dest must be wave-uniform base
// (HW writes base + lane*16).
#define GLD16(gptr, lptr)                                                      \
  __builtin_amdgcn_global_load_lds(                                            \
      (__attribute__((address_space(1))) unsigned int*)(gptr),                 \
      (__attribute__((address_space(3))) unsigned int*)(lptr), 16, 0, 0)

// ---------------------------------------------------------------------------
// Input dtype detector. If the buffer holds bf16 pairs, the LOW 16 bits of a
// 32-bit word are a bf16 of N(0,1): exponent field in ~[100,140] essentially
// always. If it holds fp32, the low 16 bits are mantissa bits: uniform
// exponent field, in-range only ~16% of the time. flag=1 -> inputs are bf16.
// ---------------------------------------------------------------------------
__global__ __launch_bounds__(256)
void detect_kernel(const unsigned int* __restrict__ x, int* __restrict__ flag)
{
    __shared__ int sred[4];
    const int tid = threadIdx.x;
    int cnt = 0;
#pragma unroll
    for (int i = 0; i < 16; ++i) {
        const unsigned w = x[tid * 16 + i];
        const unsigned e = (w >> 7) & 0xFF;
        cnt += (e >= 100 && e <= 140) ? 1 : 0;
    }
#pragma unroll
    for (int off = 32; off > 0; off >>= 1) cnt += __shfl_xor(cnt, off);
    if ((tid & 63) == 0) sred[tid >> 6] = cnt;
    __syncthreads();
    if (tid == 0) {
        const int t = sred[0] + sred[1] + sred[2] + sred[3];
        *flag = (t > 2048) ? 1 : 0;   // of 4096 sampled words
    }
}

// ---------------------------------------------------------------------------
// Convert any input tensor to a bf16 ws copy (pure copy if already bf16).
// n8 = n/8 (all tensor sizes here are multiples of 8).
// ---------------------------------------------------------------------------
__global__ __launch_bounds__(256)
void convert_kernel(const void* __restrict__ src, bf16* __restrict__ dst,
                    int n8, const int* __restrict__ flag)
{
    const int j = blockIdx.x * 256 + threadIdx.x;
    if (j >= n8) return;
    if (flag[0]) {
        ((bf16x8*)dst)[j] = ((const bf16x8*)src)[j];
    } else {
        const float* s = (const float*)src + (size_t)j * 8;
        bf16x8 o;
#pragma unroll
        for (int e = 0; e < 8; ++e) o[e] = (bf16)s[e];
        ((bf16x8*)dst)[j] = o;
    }
}

// ---------------------------------------------------------------------------
// LayerNorm over H=1024, one block (256 thr) per row, bf16x4 loads.
// ---------------------------------------------------------------------------
__global__ __launch_bounds__(256)
void ln_kernel(const bf16* __restrict__ x, const bf16* __restrict__ w,
               const bf16* __restrict__ b, bf16* __restrict__ out)
{
    __shared__ float red[8];
    const int row = blockIdx.x;
    const int tid = threadIdx.x;
    const bf16* xr = x + (size_t)row * 1024;
    bf16x4 xv = *(const bf16x4*)(xr + tid * 4);
    float xf[4], s = 0.f, ss = 0.f;
#pragma unroll
    for (int j = 0; j < 4; ++j) { xf[j] = (float)xv[j]; s += xf[j]; ss += xf[j] * xf[j]; }
#pragma unroll
    for (int off = 32; off > 0; off >>= 1) { s += __shfl_xor(s, off); ss += __shfl_xor(ss, off); }
    if ((tid & 63) == 0) { red[(tid >> 6) * 2] = s; red[(tid >> 6) * 2 + 1] = ss; }
    __syncthreads();
    s  = red[0] + red[2] + red[4] + red[6];
    ss = red[1] + red[3] + red[5] + red[7];
    const float mu   = s * (1.f / 1024.f);
    const float var  = ss * (1.f / 1024.f) - mu * mu;
    const float rstd = rsqrtf(var + 1e-12f);
    bf16x4 wv = *(const bf16x4*)(w + tid * 4);
    bf16x4 bv = *(const bf16x4*)(b + tid * 4);
    bf16x4 ov;
#pragma unroll
    for (int j = 0; j < 4; ++j)
        ov[j] = (bf16)((xf[j] - mu) * rstd * (float)wv[j] + (float)bv[j]);
    *(bf16x4*)(out + (size_t)row * 1024 + tid * 4) = ov;
}

// ---------------------------------------------------------------------------
// C[M,N] = A[M,K] @ W[N,K]^T + bias (+ res). m97 structure: 128x128 tile,
// BK=32, 4 waves each owning a 64x64 quadrant (4x4 fragments of 16x16x32).
// OUT_DYN: store dtype chosen at runtime from *flag (bf16 if 1, fp32 if 0).
// ---------------------------------------------------------------------------
template<bool HAS_RES, bool OUT_DYN>
__global__ __launch_bounds__(256)
void gemm_bt(const bf16* __restrict__ A, const bf16* __restrict__ W,
             const bf16* __restrict__ bias, const bf16* __restrict__ res,
             void* __restrict__ Cv, const int* __restrict__ flag,
             int M, int N, int K)
{
    __shared__ alignas(16) bf16 As[128][32];
    __shared__ alignas(16) bf16 Bs[128][32];
    const int tid  = threadIdx.x;
    const int lane = tid & 63, wid = tid >> 6;
    const int lr = lane & 15, lg = lane >> 4;
    const int kgrp = lg * 8;                      // A/B frag: k = (lane>>4)*8 + i
    const int wm = (wid >> 1) * 64, wn = (wid & 1) * 64;
    const int row0 = blockIdx.x * 128, col0 = blockIdx.y * 128;

    f32x4 acc[4][4] = {};

    for (int k0 = 0; k0 < K; k0 += 32) {
#pragma unroll
        for (int i = 0; i < 2; ++i) {
            const int c = i * 256 + tid;          // 512 x 16B chunks per tile
            const int r = c >> 2, k8 = (c & 3) * 8;
            GLD16(A + (size_t)(row0 + r) * K + k0 + k8,
                  (char*)&As[0][0] + (size_t)(i * 256 + wid * 64) * 16);
            GLD16(W + (size_t)(col0 + r) * K + k0 + k8,
                  (char*)&Bs[0][0] + (size_t)(i * 256 + wid * 64) * 16);
        }
        __syncthreads();
        bf16x8 af[4], bw[4];
#pragma unroll
        for (int mi = 0; mi < 4; ++mi) af[mi] = *(const bf16x8*)&As[wm + mi * 16 + lr][kgrp];
#pragma unroll
        for (int ni = 0; ni < 4; ++ni) bw[ni] = *(const bf16x8*)&Bs[wn + ni * 16 + lr][kgrp];
#pragma unroll
        for (int mi = 0; mi < 4; ++mi)
#pragma unroll
            for (int ni = 0; ni < 4; ++ni)
                acc[mi][ni] = __builtin_amdgcn_mfma_f32_16x16x32_bf16(
                    af[mi], bw[ni], acc[mi][ni], 0, 0, 0);
        __syncthreads();
    }

    const bool bf16out = OUT_DYN ? (flag[0] != 0) : true;
    // C/D layout (m89-verified): col = lane&15, row = (lane>>4)*4 + reg
#pragma unroll
    for (int ni = 0; ni < 4; ++ni) {
        const int ccol = col0 + wn + ni * 16 + lr;
        const float bv = (float)bias[ccol];
#pragma unroll
        for (int mi = 0; mi < 4; ++mi)
#pragma unroll
            for (int r = 0; r < 4; ++r) {
                const size_t crow = (size_t)(row0 + wm + mi * 16 + lg * 4 + r);
                float v = acc[mi][ni][r] + bv;
                if constexpr (HAS_RES) v += (float)res[crow * N + ccol];
                if constexpr (OUT_DYN) {
                    if (bf16out) ((bf16*)Cv)[crow * N + ccol] = (bf16)v;
                    else         ((float*)Cv)[crow * N + ccol] = v;
                } else {
                    ((bf16*)Cv)[crow * N + ccol] = (bf16)v;
                }
            }
    }
}

// ---------------------------------------------------------------------------
// RoPE + rearrange qkv[4096,3072] -> q_r/k_r/v_r [64 bh][1024 s][64 hd].
// inv_freq[i] = 10000^(-i/32), cos/sin shared by halves i and i+32.
// ---------------------------------------------------------------------------
__global__ __launch_bounds__(256)
void rope_kernel(const bf16* __restrict__ qkv, bf16* __restrict__ q_r,
                 bf16* __restrict__ k_r, bf16* __restrict__ v_r)
{
    const int g  = blockIdx.x * 256 + threadIdx.x;   // [bs 4096][h 16][i 32]
    const int i  = g & 31;
    const int h  = (g >> 5) & 15;
    const int bs = g >> 9;
    const int s  = bs & 1023;
    const bf16* base = qkv + (size_t)bs * 3072;
    const float inv = __expf((float)i * (-9.210340371976184f / 32.f)); // 10000^(-i/32)
    const float ang = (float)s * inv;
    float sn, c;
    sincosf(ang, &sn, &c);
    const int qoff = h * 64 + i;
    const float ql = (float)base[qoff],        qh = (float)base[qoff + 32];
    const float kl = (float)base[1024 + qoff], kh = (float)base[1024 + qoff + 32];
    const size_t ob = ((size_t)((bs >> 10) * 16 + h) * 1024 + s) * 64;
    q_r[ob + i]      = (bf16)(ql * c - qh * sn);
    q_r[ob + i + 32] = (bf16)(qh * c + ql * sn);
    k_r[ob + i]      = (bf16)(kl * c - kh * sn);
    k_r[ob + i + 32] = (bf16)(kh * c + kl * sn);
    v_r[ob + i]      = base[2048 + qoff];
    v_r[ob + i + 32] = base[2048 + qoff + 32];
}

// ---------------------------------------------------------------------------
// Flash attention, causal, scale=1/8. Block = 4 waves = 64 q-rows of one
// (b,head). KV chunks of 64. LDS rows padded to 72 elems (144B) so 16-lane
// fragment reads land on distinct banks (2-way max, free per m136).
// ---------------------------------------------------------------------------
__global__ __launch_bounds__(256)
void attn_kernel(const bf16* __restrict__ q_r, const bf16* __restrict__ k_r,
                 const bf16* __restrict__ v_r, bf16* __restrict__ attn)
{
    __shared__ alignas(16) bf16 Ks[64][72];      // K chunk, [kv][hd]
    __shared__ alignas(16) bf16 Vt[64][72];      // V chunk transposed, [hd][kv]
    __shared__ alignas(16) bf16 Ps[4][16][72];   // per-wave P tile, [q][kv]
    const int qt = blockIdx.x, bh = blockIdx.y;
    const int tid = threadIdx.x, lane = tid & 63, w = tid >> 6;
    const int lr = lane & 15, lg = lane >> 4;
    const int kgrp = lg * 8;
    const int qbase = qt * 64;

    const bf16* qrow = q_r + ((size_t)bh * 1024 + qbase + w * 16 + lr) * 64;
    const bf16x8 qf0 = *(const bf16x8*)(qrow + kgrp);
    const bf16x8 qf1 = *(const bf16x8*)(qrow + 32 + kgrp);

    f32x4 o[4] = {};
    float m_r[4], l_r[4];
#pragma unroll
    for (int r = 0; r < 4; ++r) { m_r[r] = -1e30f; l_r[r] = 0.f; }

    const int nchunk = qt + 1;
    for (int ic = 0; ic < nchunk; ++ic) {
        const int kb = ic * 64;
        __syncthreads();   // previous chunk fully consumed
#pragma unroll
        for (int i = 0; i < 2; ++i) {
            const int c = i * 256 + tid;          // 512 x 16B chunks
            const int row = c >> 3, e8 = (c & 7) * 8;
            *(bf16x8*)&Ks[row][e8] =
                *(const bf16x8*)(k_r + ((size_t)bh * 1024 + kb + row) * 64 + e8);
            const bf16x8 vv =
                *(const bf16x8*)(v_r + ((size_t)bh * 1024 + kb + row) * 64 + e8);
#pragma unroll
            for (int j = 0; j < 8; ++j) Vt[e8 + j][row] = vv[j];
        }
        __syncthreads();

        // S = Q K^T (16 q-rows x 64 kv-cols per wave)
        f32x4 sv[4] = {};
#pragma unroll
        for (int nb = 0; nb < 4; ++nb) {
            const bf16x8 kf0 = *(const bf16x8*)&Ks[nb * 16 + lr][kgrp];
            const bf16x8 kf1 = *(const bf16x8*)&Ks[nb * 16 + lr][32 + kgrp];
            sv[nb] = __builtin_amdgcn_mfma_f32_16x16x32_bf16(qf0, kf0, sv[nb], 0, 0, 0);
            sv[nb] = __builtin_amdgcn_mfma_f32_16x16x32_bf16(qf1, kf1, sv[nb], 0, 0, 0);
        }

        const bool diag = (kb == qbase);
        float pv[4][4];
#pragma unroll
        for (int r = 0; r < 4; ++r) {
            float s0[4];
#pragma unroll
            for (int nb = 0; nb < 4; ++nb) {
                float t = sv[nb][r] * 0.125f;
                if (diag && (nb * 16 + lr) > (w * 16 + lg * 4 + r)) t = -10000.f;
                s0[nb] = t;
            }
            float rm = fmaxf(fmaxf(s0[0], s0[1]), fmaxf(s0[2], s0[3]));
#pragma unroll
            for (int off = 1; off < 16; off <<= 1) rm = fmaxf(rm, __shfl_xor(rm, off));
            const float nm = fmaxf(m_r[r], rm);
            const float sc = __expf(m_r[r] - nm);
            float rs = 0.f;
#pragma unroll
            for (int nb = 0; nb < 4; ++nb) {
                const float p = __expf(s0[nb] - nm);
                pv[nb][r] = p; rs += p;
            }
#pragma unroll
            for (int off = 1; off < 16; off <<= 1) rs += __shfl_xor(rs, off);
            l_r[r] = l_r[r] * sc + rs;
            m_r[r] = nm;
#pragma unroll
            for (int nb = 0; nb < 4; ++nb) o[nb][r] *= sc;
        }

        // stash P (bf16) in per-wave LDS tile, then O += P V
#pragma unroll
        for (int nb = 0; nb < 4; ++nb)
#pragma unroll
            for (int r = 0; r < 4; ++r)
                Ps[w][lg * 4 + r][nb * 16 + lr] = (bf16)pv[nb][r];
#pragma unroll
        for (int nb = 0; nb < 4; ++nb)
#pragma unroll
            for (int ks = 0; ks < 2; ++ks) {
                const bf16x8 pa = *(const bf16x8*)&Ps[w][lr][ks * 32 + kgrp];
                const bf16x8 vb = *(const bf16x8*)&Vt[nb * 16 + lr][ks * 32 + kgrp];
                o[nb] = __builtin_amdgcn_mfma_f32_16x16x32_bf16(pa, vb, o[nb], 0, 0, 0);
            }
    }

    // write attn in [b, s, h] layout (heads re-interleaved)
    const int b = bh >> 4, head = bh & 15;
#pragma unroll
    for (int nb = 0; nb < 4; ++nb)
#pragma unroll
        for (int r = 0; r < 4; ++r) {
            const size_t rw = (size_t)(b * 1024 + qbase + w * 16 + lg * 4 + r);
            attn[rw * 1024 + head * 64 + nb * 16 + lr] = (bf16)(o[nb][r] / l_r[r]);
        }
}

// ---------------------------------------------------------------------------
// hid = gelu_exact(gate) * lin, gate = pre[:, :4096], lin = pre[:, 4096:]
// ---------------------------------------------------------------------------
__global__ __launch_bounds__(256)
void gelu_kernel(const bf16* __restrict__ pre, bf16* __restrict__ hid)
{
    const size_t g    = (size_t)blockIdx.x * 256 + threadIdx.x;
    const size_t base = g * 8;
    const size_t row  = base >> 12, col = base & 4095;
    const bf16x8 gt = *(const bf16x8*)(pre + row * 8192 + col);
    const bf16x8 ln = *(const bf16x8*)(pre + row * 8192 + 4096 + col);
    bf16x8 ov;
#pragma unroll
    for (int j = 0; j < 8; ++j) {
        const float xg = (float)gt[j];
        const float ge = 0.5f * xg * (1.f + erff(xg * 0.70710678118654752f));
        ov[j] = (bf16)(ge * (float)ln[j]);
    }
    *(bf16x8*)(hid + row * 4096 + col) = ov;
}

// ---------------------------------------------------------------------------
extern "C" void kernel_launch(void* const* d_in, const int* in_sizes, int n_in,
                              void* d_out, int out_size, void* d_ws, size_t ws_size,
                              hipStream_t stream)
{
    char* ws = (char*)d_ws;
    const size_t MB = 1024 * 1024;
    const size_t KB = 1024;

    // pipeline buffers (phase 2 aliases phase 1's [0,64MB) as `pre`)
    bf16* h_ln    = (bf16*)(ws + 0);         //  8 MB
    bf16* qkv     = (bf16*)(ws + 8 * MB);    // 24 MB
    bf16* q_r     = (bf16*)(ws + 32 * MB);   //  8 MB
    bf16* k_r     = (bf16*)(ws + 40 * MB);   //  8 MB
    bf16* v_r     = (bf16*)(ws + 48 * MB);   //  8 MB
    bf16* attn    = (bf16*)(ws + 56 * MB);   //  8 MB
    bf16* attnout = (bf16*)(ws + 64 * MB);   //  8 MB
    bf16* ffnln   = (bf16*)(ws + 72 * MB);   //  8 MB
    bf16* pre     = (bf16*)(ws + 0);         // 64 MB (aliases phase-1 buffers)
    bf16* hid     = (bf16*)(ws + 80 * MB);   // 32 MB

    // bf16 copies of all inputs
    bf16* x_c    = (bf16*)(ws + 112 * MB);   //  8 MB
    bf16* qkvw_c = (bf16*)(ws + 120 * MB);   //  6 MB
    bf16* outw_c = (bf16*)(ws + 126 * MB);   //  2 MB
    bf16* i2hw_c = (bf16*)(ws + 128 * MB);   // 16 MB
    bf16* h2ow_c = (bf16*)(ws + 144 * MB);   //  8 MB
    bf16* ln1w_c = (bf16*)(ws + 152 * MB + 0 * 64 * KB);
    bf16* ln1b_c = (bf16*)(ws + 152 * MB + 1 * 64 * KB);
    bf16* qkvb_c = (bf16*)(ws + 152 * MB + 2 * 64 * KB);
    bf16* outb_c = (bf16*)(ws + 152 * MB + 3 * 64 * KB);
    bf16* ln2w_c = (bf16*)(ws + 152 * MB + 4 * 64 * KB);
    bf16* ln2b_c = (bf16*)(ws + 152 * MB + 5 * 64 * KB);
    bf16* i2hb_c = (bf16*)(ws + 152 * MB + 6 * 64 * KB);
    bf16* h2ob_c = (bf16*)(ws + 152 * MB + 7 * 64 * KB);
    int*  flag   = (int*)(ws + 153 * MB);

    detect_kernel<<<1, 256, 0, stream>>>((const unsigned int*)d_in[0], flag);

    bf16* dsts[13] = {x_c, ln1w_c, ln1b_c, qkvw_c, qkvb_c, outw_c, outb_c,
                      ln2w_c, ln2b_c, i2hw_c, i2hb_c, h2ow_c, h2ob_c};
    for (int i = 0; i < 13; ++i) {
        const int n8 = in_sizes[i] / 8;
        convert_kernel<<<(n8 + 255) / 256, 256, 0, stream>>>(d_in[i], dsts[i], n8, flag);
    }

    ln_kernel<<<4096, 256, 0, stream>>>(x_c, ln1w_c, ln1b_c, h_ln);
    gemm_bt<false, false><<<dim3(32, 24), 256, 0, stream>>>(
        h_ln, qkvw_c, qkvb_c, nullptr, qkv, nullptr, 4096, 3072, 1024);
    rope_kernel<<<8192, 256, 0, stream>>>(qkv, q_r, k_r, v_r);
    attn_kernel<<<dim3(16, 64), 256, 0, stream>>>(q_r, k_r, v_r, attn);
    gemm_bt<true, false><<<dim3(32, 8), 256, 0, stream>>>(
        attn, outw_c, outb_c, x_c, attnout, nullptr, 4096, 1024, 1024);
    ln_kernel<<<4096, 256, 0, stream>>>(attnout, ln2w_c, ln2b_c, ffnln);
    gemm_bt<false, false><<<dim3(32, 64), 256, 0, stream>>>(
        ffnln, i2hw_c, i2hb_c, nullptr, pre, nullptr, 4096, 8192, 1024);
    gelu_kernel<<<8192, 256, 0, stream>>>(pre, hid);
    gemm_bt<true, true><<<dim3(32, 8), 256, 0, stream>>>(
        hid, h2ow_c, h2ob_c, attnout, d_out, flag, 4096, 1024, 4096);
}

// Round 4
// 484.707 us; speedup vs baseline: 1.1654x; 1.1654x over previous
//
#include <hip/hip_runtime.h>
#include <cstdint>
#include <cstddef>

typedef __bf16 bf16;
typedef __bf16 bf16x4 __attribute__((ext_vector_type(4)));
typedef __bf16 bf16x8 __attribute__((ext_vector_type(8)));
typedef float  f32x4  __attribute__((ext_vector_type(4)));

// Direct global->LDS DMA, 16B per lane. LDS dest must be wave-uniform base
// (HW writes base + lane*16).
#define GLD16(gptr, lptr)                                                      \
  __builtin_amdgcn_global_load_lds(                                            \
      (__attribute__((address_space(1))) unsigned int*)(gptr),                 \
      (__attribute__((address_space(3))) unsigned int*)(lptr), 16, 0, 0)

// ---------------------------------------------------------------------------
// fp32 -> bf16 conversion for the 4 big weight matrices (GLD16 needs bf16).
// ---------------------------------------------------------------------------
__global__ __launch_bounds__(256)
void convert_kernel(const float* __restrict__ src, bf16* __restrict__ dst, int n8)
{
    const int j = blockIdx.x * 256 + threadIdx.x;
    if (j >= n8) return;
    const float* s = src + (size_t)j * 8;
    bf16x8 o;
#pragma unroll
    for (int e = 0; e < 8; ++e) o[e] = (bf16)s[e];
    ((bf16x8*)dst)[j] = o;
}

// ---------------------------------------------------------------------------
// LayerNorm over H=1024, one block (256 thr) per row. InT = float (x) or
// bf16 (attnout). Weights/bias read as fp32 directly from d_in.
// ---------------------------------------------------------------------------
template<class InT>
__global__ __launch_bounds__(256)
void ln_kernel(const InT* __restrict__ x, const float* __restrict__ w,
               const float* __restrict__ b, bf16* __restrict__ out)
{
    __shared__ float red[8];
    const int row = blockIdx.x;
    const int tid = threadIdx.x;
    const InT* xr = x + (size_t)row * 1024;
    float xf[4], s = 0.f, ss = 0.f;
#pragma unroll
    for (int j = 0; j < 4; ++j) {
        xf[j] = (float)xr[tid * 4 + j];
        s += xf[j]; ss += xf[j] * xf[j];
    }
#pragma unroll
    for (int off = 32; off > 0; off >>= 1) { s += __shfl_xor(s, off); ss += __shfl_xor(ss, off); }
    if ((tid & 63) == 0) { red[(tid >> 6) * 2] = s; red[(tid >> 6) * 2 + 1] = ss; }
    __syncthreads();
    s  = red[0] + red[2] + red[4] + red[6];
    ss = red[1] + red[3] + red[5] + red[7];
    const float mu   = s * (1.f / 1024.f);
    const float var  = ss * (1.f / 1024.f) - mu * mu;
    const float rstd = rsqrtf(var + 1e-12f);
    bf16x4 ov;
#pragma unroll
    for (int j = 0; j < 4; ++j)
        ov[j] = (bf16)((xf[j] - mu) * rstd * w[tid * 4 + j] + b[tid * 4 + j]);
    *(bf16x4*)(out + (size_t)row * 1024 + tid * 4) = ov;
}

// ---------------------------------------------------------------------------
// C[M,N] = A[M,K] @ W[N,K]^T + bias (+ res). m97 structure: 128x128 tile,
// BK=32, 4 waves each owning a 64x64 quadrant (4x4 frags of 16x16x32).
// RES_MODE: 0 none, 1 fp32 residual, 2 bf16 residual. OUT_F32: fp32 store.
// ---------------------------------------------------------------------------
template<int RES_MODE, bool OUT_F32>
__global__ __launch_bounds__(256)
void gemm_bt(const bf16* __restrict__ A, const bf16* __restrict__ W,
             const float* __restrict__ bias, const void* __restrict__ res,
             void* __restrict__ Cv, int M, int N, int K)
{
    __shared__ alignas(16) bf16 As[128][32];
    __shared__ alignas(16) bf16 Bs[128][32];
    const int tid  = threadIdx.x;
    const int lane = tid & 63, wid = tid >> 6;
    const int lr = lane & 15, lg = lane >> 4;
    const int kgrp = lg * 8;                      // A/B frag: k = (lane>>4)*8 + i
    const int wm = (wid >> 1) * 64, wn = (wid & 1) * 64;
    const int row0 = blockIdx.x * 128, col0 = blockIdx.y * 128;

    f32x4 acc[4][4] = {};

    for (int k0 = 0; k0 < K; k0 += 32) {
#pragma unroll
        for (int i = 0; i < 2; ++i) {
            const int c = i * 256 + tid;          // 512 x 16B chunks per tile
            const int r = c >> 2, k8 = (c & 3) * 8;
            GLD16(A + (size_t)(row0 + r) * K + k0 + k8,
                  (char*)&As[0][0] + (size_t)(i * 256 + wid * 64) * 16);
            GLD16(W + (size_t)(col0 + r) * K + k0 + k8,
                  (char*)&Bs[0][0] + (size_t)(i * 256 + wid * 64) * 16);
        }
        __syncthreads();
        bf16x8 af[4], bw[4];
#pragma unroll
        for (int mi = 0; mi < 4; ++mi) af[mi] = *(const bf16x8*)&As[wm + mi * 16 + lr][kgrp];
#pragma unroll
        for (int ni = 0; ni < 4; ++ni) bw[ni] = *(const bf16x8*)&Bs[wn + ni * 16 + lr][kgrp];
#pragma unroll
        for (int mi = 0; mi < 4; ++mi)
#pragma unroll
            for (int ni = 0; ni < 4; ++ni)
                acc[mi][ni] = __builtin_amdgcn_mfma_f32_16x16x32_bf16(
                    af[mi], bw[ni], acc[mi][ni], 0, 0, 0);
        __syncthreads();
    }

    // C/D layout (m89-verified): col = lane&15, row = (lane>>4)*4 + reg
#pragma unroll
    for (int ni = 0; ni < 4; ++ni) {
        const int ccol = col0 + wn + ni * 16 + lr;
        const float bv = bias[ccol];
#pragma unroll
        for (int mi = 0; mi < 4; ++mi)
#pragma unroll
            for (int r = 0; r < 4; ++r) {
                const size_t crow = (size_t)(row0 + wm + mi * 16 + lg * 4 + r);
                float v = acc[mi][ni][r] + bv;
                if constexpr (RES_MODE == 1) v += ((const float*)res)[crow * N + ccol];
                if constexpr (RES_MODE == 2) v += (float)((const bf16*)res)[crow * N + ccol];
                if constexpr (OUT_F32) ((float*)Cv)[crow * N + ccol] = v;
                else                   ((bf16*)Cv)[crow * N + ccol] = (bf16)v;
            }
    }
}

// ---------------------------------------------------------------------------
// Fused i2h + gated exact-GELU. W is i2h_w[8192,1024]; block (bx,by) computes
// hid[bx*128.., by*64..]: gate cols by*64 (W rows by*64..) and lin cols
// (W rows 4096+by*64..). 128x64 tile per matrix, waves 2x2 each 64x32.
// hid = gelu(gate_acc+bias_g) * (lin_acc+bias_l), all fp32 pre-rounding.
// ---------------------------------------------------------------------------
__global__ __launch_bounds__(256)
void gemm_i2h_gelu(const bf16* __restrict__ A, const bf16* __restrict__ W,
                   const float* __restrict__ bias, bf16* __restrict__ hid)
{
    __shared__ alignas(16) bf16 As[128][32];
    __shared__ alignas(16) bf16 Bg[64][32];
    __shared__ alignas(16) bf16 Bl[64][32];
    const int tid  = threadIdx.x;
    const int lane = tid & 63, wid = tid >> 6;
    const int lr = lane & 15, lg = lane >> 4;
    const int kgrp = lg * 8;
    const int wm = (wid >> 1) * 64, wn = (wid & 1) * 32;
    const int row0 = blockIdx.x * 128, col0 = blockIdx.y * 64;
    const int K = 1024;

    f32x4 accg[4][2] = {}, accl[4][2] = {};

    for (int k0 = 0; k0 < K; k0 += 32) {
#pragma unroll
        for (int i = 0; i < 2; ++i) {            // A: 512 chunks
            const int c = i * 256 + tid;
            const int r = c >> 2, k8 = (c & 3) * 8;
            GLD16(A + (size_t)(row0 + r) * K + k0 + k8,
                  (char*)&As[0][0] + (size_t)(i * 256 + wid * 64) * 16);
        }
        {                                         // Bg, Bl: 256 chunks each
            const int r = tid >> 2, k8 = (tid & 3) * 8;
            GLD16(W + (size_t)(col0 + r) * K + k0 + k8,
                  (char*)&Bg[0][0] + (size_t)(wid * 64) * 16);
            GLD16(W + (size_t)(4096 + col0 + r) * K + k0 + k8,
                  (char*)&Bl[0][0] + (size_t)(wid * 64) * 16);
        }
        __syncthreads();
        bf16x8 af[4], bg[2], bl[2];
#pragma unroll
        for (int mi = 0; mi < 4; ++mi) af[mi] = *(const bf16x8*)&As[wm + mi * 16 + lr][kgrp];
#pragma unroll
        for (int ni = 0; ni < 2; ++ni) {
            bg[ni] = *(const bf16x8*)&Bg[wn + ni * 16 + lr][kgrp];
            bl[ni] = *(const bf16x8*)&Bl[wn + ni * 16 + lr][kgrp];
        }
#pragma unroll
        for (int mi = 0; mi < 4; ++mi)
#pragma unroll
            for (int ni = 0; ni < 2; ++ni) {
                accg[mi][ni] = __builtin_amdgcn_mfma_f32_16x16x32_bf16(
                    af[mi], bg[ni], accg[mi][ni], 0, 0, 0);
                accl[mi][ni] = __builtin_amdgcn_mfma_f32_16x16x32_bf16(
                    af[mi], bl[ni], accl[mi][ni], 0, 0, 0);
            }
        __syncthreads();
    }

#pragma unroll
    for (int ni = 0; ni < 2; ++ni) {
        const int gc = col0 + wn + ni * 16 + lr;      // hid col / gate index
        const float bg_ = bias[gc], bl_ = bias[4096 + gc];
#pragma unroll
        for (int mi = 0; mi < 4; ++mi)
#pragma unroll
            for (int r = 0; r < 4; ++r) {
                const size_t crow = (size_t)(row0 + wm + mi * 16 + lg * 4 + r);
                const float g = accg[mi][ni][r] + bg_;
                const float l = accl[mi][ni][r] + bl_;
                const float ge = 0.5f * g * (1.f + erff(g * 0.70710678118654752f));
                hid[crow * 4096 + gc] = (bf16)(ge * l);
            }
    }
}

// ---------------------------------------------------------------------------
// RoPE + rearrange qkv[4096,3072] -> q_r/k_r/v_r [64 bh][1024 s][64 hd].
// inv_freq[i] = 10000^(-i/32), cos/sin shared by halves i and i+32.
// ---------------------------------------------------------------------------
__global__ __launch_bounds__(256)
void rope_kernel(const bf16* __restrict__ qkv, bf16* __restrict__ q_r,
                 bf16* __restrict__ k_r, bf16* __restrict__ v_r)
{
    const int g  = blockIdx.x * 256 + threadIdx.x;   // [bs 4096][h 16][i 32]
    const int i  = g & 31;
    const int h  = (g >> 5) & 15;
    const int bs = g >> 9;
    const int s  = bs & 1023;
    const bf16* base = qkv + (size_t)bs * 3072;
    const float inv = __expf((float)i * (-9.210340371976184f / 32.f)); // 10000^(-i/32)
    const float ang = (float)s * inv;
    float sn, c;
    sincosf(ang, &sn, &c);
    const int qoff = h * 64 + i;
    const float ql = (float)base[qoff],        qh = (float)base[qoff + 32];
    const float kl = (float)base[1024 + qoff], kh = (float)base[1024 + qoff + 32];
    const size_t ob = ((size_t)((bs >> 10) * 16 + h) * 1024 + s) * 64;
    q_r[ob + i]      = (bf16)(ql * c - qh * sn);
    q_r[ob + i + 32] = (bf16)(qh * c + ql * sn);
    k_r[ob + i]      = (bf16)(kl * c - kh * sn);
    k_r[ob + i + 32] = (bf16)(kh * c + kl * sn);
    v_r[ob + i]      = base[2048 + qoff];
    v_r[ob + i + 32] = base[2048 + qoff + 32];
}

// ---------------------------------------------------------------------------
// Flash attention, causal, scale=1/8. Block = 4 waves = 64 q-rows of one
// (b,head). KV chunks of 64. LDS rows padded to 72 elems (144B) so 16-lane
// fragment reads land on distinct banks (2-way max, free per m136).
// ---------------------------------------------------------------------------
__global__ __launch_bounds__(256)
void attn_kernel(const bf16* __restrict__ q_r, const bf16* __restrict__ k_r,
                 const bf16* __restrict__ v_r, bf16* __restrict__ attn)
{
    __shared__ alignas(16) bf16 Ks[64][72];      // K chunk, [kv][hd]
    __shared__ alignas(16) bf16 Vt[64][72];      // V chunk transposed, [hd][kv]
    __shared__ alignas(16) bf16 Ps[4][16][72];   // per-wave P tile, [q][kv]
    const int qt = blockIdx.x, bh = blockIdx.y;
    const int tid = threadIdx.x, lane = tid & 63, w = tid >> 6;
    const int lr = lane & 15, lg = lane >> 4;
    const int kgrp = lg * 8;
    const int qbase = qt * 64;

    const bf16* qrow = q_r + ((size_t)bh * 1024 + qbase + w * 16 + lr) * 64;
    const bf16x8 qf0 = *(const bf16x8*)(qrow + kgrp);
    const bf16x8 qf1 = *(const bf16x8*)(qrow + 32 + kgrp);

    f32x4 o[4] = {};
    float m_r[4], l_r[4];
#pragma unroll
    for (int r = 0; r < 4; ++r) { m_r[r] = -1e30f; l_r[r] = 0.f; }

    const int nchunk = qt + 1;
    for (int ic = 0; ic < nchunk; ++ic) {
        const int kb = ic * 64;
        __syncthreads();   // previous chunk fully consumed
#pragma unroll
        for (int i = 0; i < 2; ++i) {
            const int c = i * 256 + tid;          // 512 x 16B chunks
            const int row = c >> 3, e8 = (c & 7) * 8;
            *(bf16x8*)&Ks[row][e8] =
                *(const bf16x8*)(k_r + ((size_t)bh * 1024 + kb + row) * 64 + e8);
            const bf16x8 vv =
                *(const bf16x8*)(v_r + ((size_t)bh * 1024 + kb + row) * 64 + e8);
#pragma unroll
            for (int j = 0; j < 8; ++j) Vt[e8 + j][row] = vv[j];
        }
        __syncthreads();

        // S = Q K^T (16 q-rows x 64 kv-cols per wave)
        f32x4 sv[4] = {};
#pragma unroll
        for (int nb = 0; nb < 4; ++nb) {
            const bf16x8 kf0 = *(const bf16x8*)&Ks[nb * 16 + lr][kgrp];
            const bf16x8 kf1 = *(const bf16x8*)&Ks[nb * 16 + lr][32 + kgrp];
            sv[nb] = __builtin_amdgcn_mfma_f32_16x16x32_bf16(qf0, kf0, sv[nb], 0, 0, 0);
            sv[nb] = __builtin_amdgcn_mfma_f32_16x16x32_bf16(qf1, kf1, sv[nb], 0, 0, 0);
        }

        const bool diag = (kb == qbase);
        float pv[4][4];
#pragma unroll
        for (int r = 0; r < 4; ++r) {
            float s0[4];
#pragma unroll
            for (int nb = 0; nb < 4; ++nb) {
                float t = sv[nb][r] * 0.125f;
                if (diag && (nb * 16 + lr) > (w * 16 + lg * 4 + r)) t = -10000.f;
                s0[nb] = t;
            }
            float rm = fmaxf(fmaxf(s0[0], s0[1]), fmaxf(s0[2], s0[3]));
#pragma unroll
            for (int off = 1; off < 16; off <<= 1) rm = fmaxf(rm, __shfl_xor(rm, off));
            const float nm = fmaxf(m_r[r], rm);
            const float sc = __expf(m_r[r] - nm);
            float rs = 0.f;
#pragma unroll
            for (int nb = 0; nb < 4; ++nb) {
                const float p = __expf(s0[nb] - nm);
                pv[nb][r] = p; rs += p;
            }
#pragma unroll
            for (int off = 1; off < 16; off <<= 1) rs += __shfl_xor(rs, off);
            l_r[r] = l_r[r] * sc + rs;
            m_r[r] = nm;
#pragma unroll
            for (int nb = 0; nb < 4; ++nb) o[nb][r] *= sc;
        }

        // stash P (bf16) in per-wave LDS tile, then O += P V
#pragma unroll
        for (int nb = 0; nb < 4; ++nb)
#pragma unroll
            for (int r = 0; r < 4; ++r)
                Ps[w][lg * 4 + r][nb * 16 + lr] = (bf16)pv[nb][r];
#pragma unroll
        for (int nb = 0; nb < 4; ++nb)
#pragma unroll
            for (int ks = 0; ks < 2; ++ks) {
                const bf16x8 pa = *(const bf16x8*)&Ps[w][lr][ks * 32 + kgrp];
                const bf16x8 vb = *(const bf16x8*)&Vt[nb * 16 + lr][ks * 32 + kgrp];
                o[nb] = __builtin_amdgcn_mfma_f32_16x16x32_bf16(pa, vb, o[nb], 0, 0, 0);
            }
    }

    // write attn in [b, s, h] layout (heads re-interleaved)
    const int b = bh >> 4, head = bh & 15;
#pragma unroll
    for (int nb = 0; nb < 4; ++nb)
#pragma unroll
        for (int r = 0; r < 4; ++r) {
            const size_t rw = (size_t)(b * 1024 + qbase + w * 16 + lg * 4 + r);
            attn[rw * 1024 + head * 64 + nb * 16 + lr] = (bf16)(o[nb][r] / l_r[r]);
        }
}

// ---------------------------------------------------------------------------
extern "C" void kernel_launch(void* const* d_in, const int* in_sizes, int n_in,
                              void* d_out, int out_size, void* d_ws, size_t ws_size,
                              hipStream_t stream)
{
    const float* x    = (const float*)d_in[0];
    const float* ln1w = (const float*)d_in[1];
    const float* ln1b = (const float*)d_in[2];
    const float* qkvw = (const float*)d_in[3];
    const float* qkvb = (const float*)d_in[4];
    const float* outw = (const float*)d_in[5];
    const float* outb = (const float*)d_in[6];
    const float* ln2w = (const float*)d_in[7];
    const float* ln2b = (const float*)d_in[8];
    const float* i2hw = (const float*)d_in[9];
    const float* i2hb = (const float*)d_in[10];
    const float* h2ow = (const float*)d_in[11];
    const float* h2ob = (const float*)d_in[12];

    char* ws = (char*)d_ws;
    const size_t MB = 1024 * 1024;

    bf16* h_ln    = (bf16*)(ws + 0);         //  8 MB
    bf16* qkv     = (bf16*)(ws + 8 * MB);    // 24 MB
    bf16* q_r     = (bf16*)(ws + 32 * MB);   //  8 MB
    bf16* k_r     = (bf16*)(ws + 40 * MB);   //  8 MB
    bf16* v_r     = (bf16*)(ws + 48 * MB);   //  8 MB
    bf16* attn    = (bf16*)(ws + 56 * MB);   //  8 MB
    bf16* attnout = (bf16*)(ws + 64 * MB);   //  8 MB
    bf16* ffnln   = (bf16*)(ws + 72 * MB);   //  8 MB
    bf16* hid     = (bf16*)(ws + 80 * MB);   // 32 MB
    bf16* qkvw_c  = (bf16*)(ws + 112 * MB);  //  6 MB
    bf16* outw_c  = (bf16*)(ws + 118 * MB);  //  2 MB
    bf16* i2hw_c  = (bf16*)(ws + 120 * MB);  // 16 MB
    bf16* h2ow_c  = (bf16*)(ws + 136 * MB);  //  8 MB  (total 144 MB)

    convert_kernel<<<1536, 256, 0, stream>>>(qkvw, qkvw_c, 3145728 / 8);
    convert_kernel<<< 512, 256, 0, stream>>>(outw, outw_c, 1048576 / 8);
    convert_kernel<<<4096, 256, 0, stream>>>(i2hw, i2hw_c, 8388608 / 8);
    convert_kernel<<<2048, 256, 0, stream>>>(h2ow, h2ow_c, 4194304 / 8);

    ln_kernel<float><<<4096, 256, 0, stream>>>(x, ln1w, ln1b, h_ln);
    gemm_bt<0, false><<<dim3(32, 24), 256, 0, stream>>>(
        h_ln, qkvw_c, qkvb, nullptr, qkv, 4096, 3072, 1024);
    rope_kernel<<<8192, 256, 0, stream>>>(qkv, q_r, k_r, v_r);
    attn_kernel<<<dim3(16, 64), 256, 0, stream>>>(q_r, k_r, v_r, attn);
    gemm_bt<1, false><<<dim3(32, 8), 256, 0, stream>>>(
        attn, outw_c, outb, x, attnout, 4096, 1024, 1024);
    ln_kernel<bf16><<<4096, 256, 0, stream>>>(attnout, ln2w, ln2b, ffnln);
    gemm_i2h_gelu<<<dim3(32, 64), 256, 0, stream>>>(ffnln, i2hw_c, i2hb, hid);
    gemm_bt<2, true><<<dim3(32, 8), 256, 0, stream>>>(
        hid, h2ow_c, h2ob, attnout, d_out, 4096, 1024, 4096);
}